// Round 1
// baseline (12094.647 us; speedup 1.0000x reference)
//
#include <hip/hip_runtime.h>
#include <math.h>

#define Bb 24
#define Ss 512
#define Dd 512
#define Hh 8
#define DFFf 2048

// ---------------- embeddings ----------------
__global__ __launch_bounds__(256) void embed_kernel(
    const int* __restrict__ q_data, const int* __restrict__ target, const int* __restrict__ pid_data,
    const float* __restrict__ q_tab, const float* __restrict__ qa_tab,
    const float* __restrict__ qd_tab, const float* __restrict__ qad_tab,
    const float* __restrict__ pid_tab,
    float* __restrict__ q_emb, float* __restrict__ x, float* __restrict__ y)
{
  int t = blockIdx.x;
  int qi = q_data[t], tg = target[t], pi = pid_data[t];
  float pd = pid_tab[pi];
  const float* qe  = q_tab  + (size_t)qi*Dd;
  const float* qa  = qa_tab + (size_t)tg*Dd;
  const float* qd  = qd_tab + (size_t)qi*Dd;
  const float* qad = qad_tab+ (size_t)tg*Dd;
  size_t base = (size_t)t*Dd;
  for (int d = threadIdx.x; d < Dd; d += 256) {
    float e = qe[d], dv = qd[d];
    float qv  = e + pd*dv;
    float qav = qa[d] + e + pd*(qad[d] + dv);
    q_emb[base+d] = qv; x[base+d] = qv; y[base+d] = qav;
  }
}

// ---------------- fp32 tiled GEMM: C = act(A[M,K]@W[K,N] + bias (+C if accum)) ----------------
// M%64==0, N%64==0, K%16==0 guaranteed by call sites.
__global__ __launch_bounds__(256) void gemm_kernel(
    const float* __restrict__ A, const float* __restrict__ W, const float* __restrict__ bias,
    float* __restrict__ C, int M, int N, int K, int act, int accum)
{
  __shared__ float As[64][17];
  __shared__ float Ws[16][65];
  int bm = blockIdx.y*64, bn = blockIdx.x*64;
  int tid = threadIdx.x;
  int tx = tid & 15, ty = tid >> 4;
  float accv[4][4];
  #pragma unroll
  for (int i=0;i<4;i++)
    #pragma unroll
    for (int j=0;j<4;j++) accv[i][j]=0.f;
  int ar = tid >> 2, ak = (tid & 3)*4;
  int wr = tid >> 4, wc = (tid & 15)*4;
  for (int k0=0; k0<K; k0+=16) {
    __syncthreads();
    float4 a4 = *(const float4*)(A + (size_t)(bm+ar)*K + k0 + ak);
    As[ar][ak]=a4.x; As[ar][ak+1]=a4.y; As[ar][ak+2]=a4.z; As[ar][ak+3]=a4.w;
    float4 w4 = *(const float4*)(W + (size_t)(k0+wr)*N + bn + wc);
    Ws[wr][wc]=w4.x; Ws[wr][wc+1]=w4.y; Ws[wr][wc+2]=w4.z; Ws[wr][wc+3]=w4.w;
    __syncthreads();
    #pragma unroll
    for (int kk=0;kk<16;kk++) {
      float av[4], wv[4];
      #pragma unroll
      for (int i=0;i<4;i++) av[i]=As[ty+16*i][kk];
      #pragma unroll
      for (int j=0;j<4;j++) wv[j]=Ws[kk][tx+16*j];
      #pragma unroll
      for (int i=0;i<4;i++)
        #pragma unroll
        for (int j=0;j<4;j++) accv[i][j] += av[i]*wv[j];
    }
  }
  float bv[4];
  #pragma unroll
  for (int j=0;j<4;j++) bv[j] = bias ? bias[bn+tx+16*j] : 0.f;
  #pragma unroll
  for (int i=0;i<4;i++) {
    size_t ro = (size_t)(bm+ty+16*i)*N + bn;
    #pragma unroll
    for (int j=0;j<4;j++) {
      float v = accv[i][j] + bv[j];
      if (accum) v += C[ro+tx+16*j];
      if (act) v = fmaxf(v, 0.f);
      C[ro+tx+16*j] = v;
    }
  }
}

// ---------------- residual + LayerNorm ----------------
__device__ __forceinline__ float blockSum256(float v) {
  __shared__ float sh[4];
  #pragma unroll
  for (int o=32;o;o>>=1) v += __shfl_down(v,o);
  if ((threadIdx.x & 63)==0) sh[threadIdx.x>>6]=v;
  __syncthreads();
  float r = sh[0]+sh[1]+sh[2]+sh[3];
  __syncthreads();
  return r;
}

__global__ __launch_bounds__(256) void add_ln_kernel(
    const float* __restrict__ xa, const float* __restrict__ xb,
    const float* __restrict__ g, const float* __restrict__ bta, float* __restrict__ out)
{
  size_t base = (size_t)blockIdx.x*Dd;
  int tid = threadIdx.x;
  float v0 = xa[base+tid]     + xb[base+tid];
  float v1 = xa[base+tid+256] + xb[base+tid+256];
  float mean = blockSum256(v0+v1) * (1.f/512.f);
  float d0 = v0-mean, d1 = v1-mean;
  float var = blockSum256(d0*d0 + d1*d1) * (1.f/512.f);
  float inv = rsqrtf(var + 1e-5f);
  out[base+tid]     = d0*inv*g[tid]     + bta[tid];
  out[base+tid+256] = d1*inv*g[tid+256] + bta[tid+256];
}

// ---------------- router: gates=softmax(ql@Wg), top-2, rmask[b,h] ----------------
__global__ __launch_bounds__(512) void router_kernel(
    const float* __restrict__ ql, const float* __restrict__ Wg, float* __restrict__ rmask)
{
  __shared__ float sh[8][7];
  int b = blockIdx.x, s = threadIdx.x;
  const float* q = ql + ((size_t)b*Ss + s)*Dd;
  float lg[7];
  #pragma unroll
  for (int k=0;k<7;k++) lg[k]=0.f;
  for (int d0=0; d0<Dd; d0+=4) {
    float4 qv = *(const float4*)(q+d0);
    float qa[4] = {qv.x,qv.y,qv.z,qv.w};
    #pragma unroll
    for (int i=0;i<4;i++)
      #pragma unroll
      for (int k=0;k<7;k++) lg[k] += qa[i]*Wg[(d0+i)*7+k];
  }
  float mx = lg[0];
  #pragma unroll
  for (int k=1;k<7;k++) mx = fmaxf(mx, lg[k]);
  float sum = 0.f, gt[7];
  #pragma unroll
  for (int k=0;k<7;k++){ gt[k]=__expf(lg[k]-mx); sum+=gt[k]; }
  float invs = 1.f/sum;
  #pragma unroll
  for (int k=0;k<7;k++) gt[k]*=invs;
  // top-2, lowest-index tie-break (matches lax.top_k)
  int i1=0; float v1=gt[0];
  #pragma unroll
  for (int k=1;k<7;k++) if (gt[k]>v1){v1=gt[k]; i1=k;}
  int i2=-1; float v2=-1e30f;
  #pragma unroll
  for (int k=0;k<7;k++) if (k!=i1 && gt[k]>v2){v2=gt[k]; i2=k;}
  #pragma unroll
  for (int k=0;k<7;k++) {
    float d = (k==i1 || k==i2) ? gt[k] : 0.f;
    #pragma unroll
    for (int o=32;o;o>>=1) d += __shfl_down(d,o);
    if ((threadIdx.x&63)==0) sh[threadIdx.x>>6][k]=d;
  }
  __syncthreads();
  if (s < 7) {
    float t=0.f;
    #pragma unroll
    for (int w=0;w<8;w++) t += sh[w][s];
    rmask[b*8 + 1 + s] = t * (1.f/512.f);
  } else if (s == 7) {
    rmask[b*8] = 1.f;
  }
}

// ---------------- attention (k==q), causal, online softmax; row 0 handled separately ----------------
__global__ __launch_bounds__(256) void attn_kernel(
    const float* __restrict__ ql, const float* __restrict__ vl,
    const float* __restrict__ rmask, float* __restrict__ ctx, int strict)
{
  __shared__ float Kt[64][64];
  __shared__ float Vt[64][64];
  int bh = blockIdx.x >> 1, half = blockIdx.x & 1;
  int b = bh >> 3, h = bh & 7;
  int wave = threadIdx.x >> 6, lane = threadIdx.x & 63;
  int row = wave*128 + half*64 + lane;   // bijective over 0..511 across (half,wave,lane)
  const float* qrow = ql + ((size_t)b*Ss + row)*Dd + h*64;
  float q[64];
  #pragma unroll
  for (int d=0; d<64; d+=4) {
    float4 t4 = *(const float4*)(qrow+d);
    q[d]=t4.x; q[d+1]=t4.y; q[d+2]=t4.z; q[d+3]=t4.w;
  }
  float o[64];
  #pragma unroll
  for (int d=0;d<64;d++) o[d]=0.f;
  float m=-3e38f, l=0.f;
  int lastA = row - strict;
  int waveLast = wave*128 + half*64 + 63 - strict;
  int nt = 7 + half;
  int sr = threadIdx.x >> 2, sc0 = (threadIdx.x & 3)*16;
  for (int t=0;t<nt;t++) {
    int j0 = t*64;
    __syncthreads();
    {
      const float* kp = ql + ((size_t)b*Ss + j0 + sr)*Dd + h*64 + sc0;
      const float* vp = vl + ((size_t)b*Ss + j0 + sr)*Dd + h*64 + sc0;
      #pragma unroll
      for (int u=0;u<16;u+=4) {
        *(float4*)&Kt[sr][sc0+u] = *(const float4*)(kp+u);
        *(float4*)&Vt[sr][sc0+u] = *(const float4*)(vp+u);
      }
    }
    __syncthreads();
    if (j0 > waveLast) continue;       // wave-uniform skip; still hits next barrier
    for (int js=0; js<64; js+=16) {
      if (j0 + js > waveLast) break;   // wave-uniform
      float sc[16]; float smax=-1e30f;
      #pragma unroll
      for (int jj=0;jj<16;jj++) {
        int j = j0+js+jj;
        float dot=0.f;
        #pragma unroll
        for (int d=0; d<64; d++) dot += q[d]*Kt[js+jj][d];
        float sv = (j <= lastA) ? dot*0.125f : -1e30f;
        sc[jj]=sv; smax=fmaxf(smax,sv);
      }
      if (smax > -1e29f) {
        float mn = fmaxf(m, smax);
        float cf = __expf(m - mn);   // m==-3e38 -> 0, correct first-time behavior
        l *= cf;
        #pragma unroll
        for (int d=0;d<64;d++) o[d]*=cf;
        m = mn;
        #pragma unroll
        for (int jj=0;jj<16;jj++) {
          float p = __expf(sc[jj]-m);  // masked lanes: exp(-1e30-m)=0
          l += p;
          #pragma unroll
          for (int d=0;d<64;d++) o[d] += p*Vt[js+jj][d];
        }
      }
    }
  }
  if (row != 0) {   // row 0 is the uniform-attention special case, written by attn_row0_kernel
    float s = rmask[b*8+h] / l;
    float* op = ctx + ((size_t)b*Ss + row)*Dd + h*64;
    #pragma unroll
    for (int d=0; d<64; d+=4) {
      float4 t4; t4.x=o[d]*s; t4.y=o[d+1]*s; t4.z=o[d+2]*s; t4.w=o[d+3]*s;
      *(float4*)(op+d)=t4;
    }
  }
}

// row 0: scores all set to 0 AFTER masking -> uniform softmax over ALL 512 positions
__global__ __launch_bounds__(64) void attn_row0_kernel(
    const float* __restrict__ vl, const float* __restrict__ rmask, float* __restrict__ ctx)
{
  int b = blockIdx.x >> 3, h = blockIdx.x & 7;
  int d = threadIdx.x;
  float s = 0.f;
  for (int j=0;j<Ss;j++) s += vl[((size_t)b*Ss+j)*Dd + h*64 + d];
  ctx[(size_t)b*Ss*Dd + h*64 + d] = s * rmask[b*8+h] * (1.f/512.f);
}

// ---------------- final dot + sigmoid ----------------
__global__ __launch_bounds__(256) void head_kernel(
    const float* __restrict__ m2, const float* __restrict__ ow3, const float* __restrict__ ob3,
    float* __restrict__ out)
{
  int wave = threadIdx.x >> 6, lane = threadIdx.x & 63;
  int t = blockIdx.x*4 + wave;
  const float* r = m2 + (size_t)t*256;
  float s = 0.f;
  #pragma unroll
  for (int c=0;c<4;c++) s += r[lane + c*64] * ow3[lane + c*64];
  #pragma unroll
  for (int o=32;o;o>>=1) s += __shfl_down(s,o);
  if (lane==0) out[t] = 1.f/(1.f + __expf(-(s + ob3[0])));
}

// ---------------- host orchestration ----------------
static inline void gemm(const float* A, const float* W, const float* bias, float* C,
                        int M, int N, int K, int act, int accum, hipStream_t s) {
  dim3 g(N/64, M/64);
  gemm_kernel<<<g, 256, 0, s>>>(A, W, bias, C, M, N, K, act, accum);
}

extern "C" void kernel_launch(void* const* d_in, const int* in_sizes, int n_in,
                              void* d_out, int out_size, void* d_ws, size_t ws_size,
                              hipStream_t stream) {
  const int*   q_data  = (const int*)d_in[0];
  const int*   target  = (const int*)d_in[1];
  const int*   pid_data= (const int*)d_in[2];
  const float* q_tab   = (const float*)d_in[3];
  const float* qa_tab  = (const float*)d_in[4];
  const float* qd_tab  = (const float*)d_in[5];
  const float* qad_tab = (const float*)d_in[6];
  const float* pid_tab = (const float*)d_in[7];
  const float* Wq = (const float*)d_in[8];
  const float* bq = (const float*)d_in[9];
  const float* Wv = (const float*)d_in[10];
  const float* bv = (const float*)d_in[11];
  const float* Wg = (const float*)d_in[12];
  const float* Wo = (const float*)d_in[13];
  const float* bo = (const float*)d_in[14];
  const float* ln1_g = (const float*)d_in[15];
  const float* ln1_b = (const float*)d_in[16];
  const float* W1 = (const float*)d_in[17];
  const float* b1 = (const float*)d_in[18];
  const float* W2 = (const float*)d_in[19];
  const float* b2 = (const float*)d_in[20];
  const float* ln2_g = (const float*)d_in[21];
  const float* ln2_b = (const float*)d_in[22];
  const float* ow1 = (const float*)d_in[23];
  const float* ob1 = (const float*)d_in[24];
  const float* ow2 = (const float*)d_in[25];
  const float* ob2 = (const float*)d_in[26];
  const float* ow3 = (const float*)d_in[27];
  const float* ob3 = (const float*)d_in[28];

  const size_t F = (size_t)Bb*Ss*Dd;          // 6,291,456 floats = 25.2 MB
  float* ws    = (float*)d_ws;
  float* q_emb = ws + 0*F;
  float* xb    = ws + 1*F;
  float* yb    = ws + 2*F;
  float* qlb   = ws + 3*F;
  float* vlb   = ws + 4*F;   // reused as x1 after attention
  float* ctxb  = ws + 5*F;   // reused as f2 after Wo GEMM
  float* tmpb  = ws + 6*F;
  float* ffb   = ws + 7*F;   // FFN hidden chunk (3072 x 2048 = same size as F)
  float* rmaskb= ws + 8*F;   // 192 floats

  const int M = Bb*Ss;       // 12288

  embed_kernel<<<M, 256, 0, stream>>>(q_data, target, pid_data, q_tab, qa_tab,
                                      qd_tab, qad_tab, pid_tab, q_emb, xb, yb);

  for (int l=0; l<6; l++) {
    float* Q        = (l<2) ? yb : xb;
    const float* Xv = (l<2) ? yb : ((l==3||l==5) ? yb : xb);
    int strict      = (l==3||l==5) ? 1 : 0;

    gemm(Q,  Wq + (size_t)l*Dd*Dd, bq + l*Dd, qlb, M, Dd, Dd, 0, 0, stream);
    gemm(Xv, Wv + (size_t)l*Dd*Dd, bv + l*Dd, vlb, M, Dd, Dd, 0, 0, stream);
    router_kernel<<<Bb, 512, 0, stream>>>(qlb, Wg + (size_t)l*Dd*7, rmaskb);
    attn_kernel<<<Bb*Hh*2, 256, 0, stream>>>(qlb, vlb, rmaskb, ctxb, strict);
    attn_row0_kernel<<<Bb*Hh, 64, 0, stream>>>(vlb, rmaskb, ctxb);
    gemm(ctxb, Wo + (size_t)l*Dd*Dd, bo + l*Dd, tmpb, M, Dd, Dd, 0, 0, stream);
    add_ln_kernel<<<M, 256, 0, stream>>>(Q, tmpb, ln1_g + l*Dd, ln1_b + l*Dd, vlb); // x1 -> vlb
    for (int c=0;c<4;c++) {  // FFN in 4 row-chunks to bound workspace
      gemm(vlb + (size_t)c*3072*Dd, W1 + (size_t)l*Dd*DFFf, b1 + l*DFFf, ffb,
           3072, DFFf, Dd, 1, 0, stream);
      gemm(ffb, W2 + (size_t)l*DFFf*Dd, b2 + l*Dd, ctxb + (size_t)c*3072*Dd,
           3072, Dd, DFFf, 0, 0, stream);
    }
    add_ln_kernel<<<M, 256, 0, stream>>>(vlb, ctxb, ln2_g + l*Dd, ln2_b + l*Dd, Q);
  }

  // head: h = [x, q_emb] @ ow1 (split-K accumulate), relu, @ow2, relu, @ow3, sigmoid
  gemm(xb,    ow1,                     nullptr, tmpb, M, 512, 512, 0, 0, stream);
  gemm(q_emb, ow1 + (size_t)512*512,   ob1,     tmpb, M, 512, 512, 1, 1, stream);
  gemm(tmpb,  ow2,                     ob2,     qlb,  M, 256, 512, 1, 0, stream);
  head_kernel<<<M/4, 256, 0, stream>>>(qlb, ow3, ob3, (float*)d_out);
}

// Round 2
// 5113.746 us; speedup vs baseline: 2.3651x; 2.3651x over previous
//
#include <hip/hip_runtime.h>
#include <math.h>

typedef unsigned short u16;
typedef unsigned int   u32;
typedef __attribute__((ext_vector_type(8))) short short8;
typedef __attribute__((ext_vector_type(4))) float f32x4;

#define Bb 24
#define Ss 512
#define Dd 512
#define DFFf 2048

// ---- bf16 helpers (RNE, matches numpy) ----
__device__ __forceinline__ u16 f2b(float f) {
  u32 u = __float_as_uint(f);
  u32 r = (u + 0x7fffu + ((u >> 16) & 1u)) >> 16;
  return (u16)r;
}
__device__ __forceinline__ float b2f(u32 h) { return __uint_as_float(h << 16); }
__device__ __forceinline__ void cvt8(uint4 p, float* d) {
  d[0]=b2f(p.x&0xffffu); d[1]=b2f(p.x>>16);
  d[2]=b2f(p.y&0xffffu); d[3]=b2f(p.y>>16);
  d[4]=b2f(p.z&0xffffu); d[5]=b2f(p.z>>16);
  d[6]=b2f(p.w&0xffffu); d[7]=b2f(p.w>>16);
}

// ---- weight transpose+convert: dst[N][K] bf16 = src[K][N] fp32 ----
__global__ __launch_bounds__(256) void trans_kernel(
    const float* __restrict__ src, u16* __restrict__ dst, int K, int N)
{
  __shared__ float t[32][33];
  int n0 = blockIdx.x*32, k0 = blockIdx.y*32;
  const float* s = src + (size_t)blockIdx.z*K*N;
  u16* d = dst + (size_t)blockIdx.z*K*N;
  int c = threadIdx.x & 31, r = threadIdx.x >> 5;
  #pragma unroll
  for (int rr=r; rr<32; rr+=8) t[rr][c] = s[(size_t)(k0+rr)*N + n0 + c];
  __syncthreads();
  #pragma unroll
  for (int rr=r; rr<32; rr+=8) d[(size_t)(n0+rr)*K + k0 + c] = f2b(t[c][rr]);
}

// ---- embeddings ----
__global__ __launch_bounds__(256) void embed_kernel(
    const int* __restrict__ q_data, const int* __restrict__ target, const int* __restrict__ pid_data,
    const float* __restrict__ q_tab, const float* __restrict__ qa_tab,
    const float* __restrict__ qd_tab, const float* __restrict__ qad_tab,
    const float* __restrict__ pid_tab,
    float* __restrict__ xb, float* __restrict__ yb,
    u16* __restrict__ qebf, u16* __restrict__ ybf)
{
  int t = blockIdx.x;
  int qi = q_data[t], tg = target[t], pi = pid_data[t];
  float pd = pid_tab[pi];
  const float* qe  = q_tab  + (size_t)qi*Dd;
  const float* qa  = qa_tab + (size_t)tg*Dd;
  const float* qd  = qd_tab + (size_t)qi*Dd;
  const float* qad = qad_tab+ (size_t)tg*Dd;
  size_t base = (size_t)t*Dd;
  for (int d = threadIdx.x; d < Dd; d += 256) {
    float e = qe[d], dv = qd[d];
    float qv  = e + pd*dv;
    float qav = qa[d] + e + pd*(qad[d] + dv);
    xb[base+d] = qv;  qebf[base+d] = f2b(qv);
    yb[base+d] = qav; ybf[base+d]  = f2b(qav);
  }
}

__global__ __launch_bounds__(256) void embed_x_kernel(
    const int* __restrict__ q_data, const int* __restrict__ pid_data,
    const float* __restrict__ q_tab, const float* __restrict__ qd_tab,
    const float* __restrict__ pid_tab, float* __restrict__ xb)
{
  int t = blockIdx.x;
  int qi = q_data[t], pi = pid_data[t];
  float pd = pid_tab[pi];
  const float* qe = q_tab + (size_t)qi*Dd;
  const float* qd = qd_tab + (size_t)qi*Dd;
  size_t base = (size_t)t*Dd;
  for (int d = threadIdx.x; d < Dd; d += 256)
    xb[base+d] = qe[d] + pd*qd[d];
}

// ---- bf16 MFMA GEMM (m97 structure): C = act(A[M,K]@Wt[N,K]^T + bias (+Acc)) ----
__global__ __launch_bounds__(256) void gemm_bf16_kernel(
    const u16* __restrict__ A, const u16* __restrict__ Wt,
    const float* __restrict__ bias, const float* __restrict__ Acc,
    float* __restrict__ Cf, u16* __restrict__ Cb,
    int M, int N, int K, int ldw, int act)
{
  __shared__ u16 As[128*32];
  __shared__ u16 Bs[128*32];
  int bm = blockIdx.y*128, bn = blockIdx.x*128;
  int wv = threadIdx.x >> 6, lane = threadIdx.x & 63;
  int wm = (wv & 1)*64, wn = (wv >> 1)*64;

  const char* gA[2]; const char* gB[2];
  u32 ldsOff[2];
  #pragma unroll
  for (int t=0; t<2; t++) {
    int flat = wv*128 + t*64 + lane;
    int row = flat >> 2, cb = (flat & 3)*16;
    gA[t] = (const char*)A  + ((size_t)(bm+row)*K  )*2 + cb;
    gB[t] = (const char*)Wt + ((size_t)(bn+row)*ldw)*2 + cb;
    ldsOff[t] = (u32)(wv*128 + t*64)*16;   // wave-uniform; HW adds lane*16
  }

  f32x4 acc[4][4];
  #pragma unroll
  for (int i=0;i<4;i++)
    #pragma unroll
    for (int j=0;j<4;j++) acc[i][j] = (f32x4){0.f,0.f,0.f,0.f};

  int mrow = lane & 15, quad = lane >> 4;

  for (int k0=0; k0<K; k0+=32) {
    __syncthreads();
    #pragma unroll
    for (int t=0; t<2; t++) {
      __builtin_amdgcn_global_load_lds(
          (const __attribute__((address_space(1))) void*)gA[t],
          (__attribute__((address_space(3))) void*)((char*)As + ldsOff[t]), 16, 0, 0);
      __builtin_amdgcn_global_load_lds(
          (const __attribute__((address_space(1))) void*)gB[t],
          (__attribute__((address_space(3))) void*)((char*)Bs + ldsOff[t]), 16, 0, 0);
      gA[t] += 64; gB[t] += 64;   // BK=32 bf16 = 64 bytes
    }
    __syncthreads();
    short8 af[4], bfr[4];
    #pragma unroll
    for (int i=0;i<4;i++) {
      af[i]  = *(const short8*)(As + (wm + i*16 + mrow)*32 + quad*8);
      bfr[i] = *(const short8*)(Bs + (wn + i*16 + mrow)*32 + quad*8);
    }
    #pragma unroll
    for (int i=0;i<4;i++)
      #pragma unroll
      for (int j=0;j<4;j++)
        acc[i][j] = __builtin_amdgcn_mfma_f32_16x16x32_bf16(af[i], bfr[j], acc[i][j], 0, 0, 0);
  }

  // C/D frag mapping (m89-verified): row=(lane>>4)*4+reg, col=lane&15
  #pragma unroll
  for (int i=0;i<4;i++) {
    #pragma unroll
    for (int r=0;r<4;r++) {
      int row = bm + wm + i*16 + quad*4 + r;
      #pragma unroll
      for (int j=0;j<4;j++) {
        int col = bn + wn + j*16 + mrow;
        float v = acc[i][j][r];
        if (bias) v += bias[col];
        if (Acc)  v += Acc[(size_t)row*N + col];
        if (act)  v = fmaxf(v, 0.f);
        if (Cf) Cf[(size_t)row*N + col] = v;
        if (Cb) Cb[(size_t)row*N + col] = f2b(v);
      }
    }
  }
}

// ---- residual + LayerNorm ----
__device__ __forceinline__ float blockSum256(float v) {
  __shared__ float sh[4];
  #pragma unroll
  for (int o=32;o;o>>=1) v += __shfl_down(v,o);
  if ((threadIdx.x & 63)==0) sh[threadIdx.x>>6]=v;
  __syncthreads();
  float r = sh[0]+sh[1]+sh[2]+sh[3];
  __syncthreads();
  return r;
}

__global__ __launch_bounds__(256) void add_ln_kernel(
    const float* __restrict__ xa, const u16* __restrict__ xbb,
    const float* __restrict__ g, const float* __restrict__ bta,
    float* __restrict__ outf, u16* __restrict__ outb)
{
  size_t base = (size_t)blockIdx.x*Dd;
  int tid = threadIdx.x;
  float v0 = xa[base+tid]     + b2f(xbb[base+tid]);
  float v1 = xa[base+tid+256] + b2f(xbb[base+tid+256]);
  float mean = blockSum256(v0+v1) * (1.f/512.f);
  float d0 = v0-mean, d1 = v1-mean;
  float var = blockSum256(d0*d0 + d1*d1) * (1.f/512.f);
  float inv = rsqrtf(var + 1e-5f);
  float r0 = d0*inv*g[tid]     + bta[tid];
  float r1 = d1*inv*g[tid+256] + bta[tid+256];
  outf[base+tid]     = r0; outb[base+tid]     = f2b(r0);
  outf[base+tid+256] = r1; outb[base+tid+256] = f2b(r1);
}

// ---- router ----
__global__ __launch_bounds__(512) void router_kernel(
    const u16* __restrict__ ql, const float* __restrict__ Wg, float* __restrict__ rmask)
{
  __shared__ float sh[8][7];
  int b = blockIdx.x, s = threadIdx.x;
  const u16* q = ql + ((size_t)b*Ss + s)*Dd;
  float lg[7];
  #pragma unroll
  for (int k=0;k<7;k++) lg[k]=0.f;
  for (int d0=0; d0<Dd; d0+=8) {
    uint4 p = *(const uint4*)(q+d0);
    float qa[8]; cvt8(p, qa);
    #pragma unroll
    for (int i=0;i<8;i++)
      #pragma unroll
      for (int k=0;k<7;k++) lg[k] += qa[i]*Wg[(d0+i)*7+k];
  }
  float mx = lg[0];
  #pragma unroll
  for (int k=1;k<7;k++) mx = fmaxf(mx, lg[k]);
  float sum = 0.f, gt[7];
  #pragma unroll
  for (int k=0;k<7;k++){ gt[k]=__expf(lg[k]-mx); sum+=gt[k]; }
  float invs = 1.f/sum;
  #pragma unroll
  for (int k=0;k<7;k++) gt[k]*=invs;
  int i1=0; float v1=gt[0];
  #pragma unroll
  for (int k=1;k<7;k++) if (gt[k]>v1){v1=gt[k]; i1=k;}
  int i2=-1; float v2=-1e30f;
  #pragma unroll
  for (int k=0;k<7;k++) if (k!=i1 && gt[k]>v2){v2=gt[k]; i2=k;}
  #pragma unroll
  for (int k=0;k<7;k++) {
    float d = (k==i1 || k==i2) ? gt[k] : 0.f;
    #pragma unroll
    for (int o=32;o;o>>=1) d += __shfl_down(d,o);
    if ((threadIdx.x&63)==0) sh[threadIdx.x>>6][k]=d;
  }
  __syncthreads();
  if (s < 7) {
    float t=0.f;
    #pragma unroll
    for (int w=0;w<8;w++) t += sh[w][s];
    rmask[b*8 + 1 + s] = t * (1.f/512.f);
  } else if (s == 7) {
    rmask[b*8] = 1.f;
  }
}

// ---- attention ----
__global__ __launch_bounds__(256) void attn_kernel(
    const u16* __restrict__ ql, const u16* __restrict__ vl,
    const float* __restrict__ rmask, u16* __restrict__ ctx, int strict)
{
  __shared__ float Kt[64][68];
  __shared__ float Vt[64][68];
  int bh = blockIdx.x >> 1, half = blockIdx.x & 1;
  int b = bh >> 3, h = bh & 7;
  int wave = threadIdx.x >> 6, lane = threadIdx.x & 63;
  int row = wave*128 + half*64 + lane;
  const u16* qrow = ql + ((size_t)b*Ss + row)*Dd + h*64;
  float q[64];
  #pragma unroll
  for (int d=0; d<64; d+=8) { uint4 p = *(const uint4*)(qrow+d); cvt8(p, q+d); }
  float o[64];
  #pragma unroll
  for (int d=0;d<64;d++) o[d]=0.f;
  float m=-3e38f, l=0.f;
  int lastA = row - strict;
  int waveLast = wave*128 + half*64 + 63 - strict;
  int nt = 7 + half;
  int sr = threadIdx.x >> 2, sc0 = (threadIdx.x & 3)*16;
  for (int t=0;t<nt;t++) {
    int j0 = t*64;
    __syncthreads();
    {
      const u16* kp = ql + ((size_t)b*Ss + j0 + sr)*Dd + h*64 + sc0;
      const u16* vp = vl + ((size_t)b*Ss + j0 + sr)*Dd + h*64 + sc0;
      uint4 p0 = *(const uint4*)kp;     uint4 p1 = *(const uint4*)(kp+8);
      uint4 p2 = *(const uint4*)vp;     uint4 p3 = *(const uint4*)(vp+8);
      cvt8(p0, &Kt[sr][sc0]); cvt8(p1, &Kt[sr][sc0+8]);
      cvt8(p2, &Vt[sr][sc0]); cvt8(p3, &Vt[sr][sc0+8]);
    }
    __syncthreads();
    if (j0 > waveLast) continue;
    for (int js=0; js<64; js+=16) {
      if (j0 + js > waveLast) break;
      float sc[16]; float smax=-1e30f;
      #pragma unroll
      for (int jj=0;jj<16;jj++) {
        int j = j0+js+jj;
        float dot=0.f;
        #pragma unroll
        for (int d=0; d<64; d++) dot += q[d]*Kt[js+jj][d];
        float sv = (j <= lastA) ? dot*0.125f : -1e30f;
        sc[jj]=sv; smax=fmaxf(smax,sv);
      }
      if (smax > -1e29f) {
        float mn = fmaxf(m, smax);
        float cf = __expf(m - mn);
        l *= cf;
        #pragma unroll
        for (int d=0;d<64;d++) o[d]*=cf;
        m = mn;
        #pragma unroll
        for (int jj=0;jj<16;jj++) {
          float p = __expf(sc[jj]-m);
          l += p;
          #pragma unroll
          for (int d=0;d<64;d++) o[d] += p*Vt[js+jj][d];
        }
      }
    }
  }
  if (row != 0) {
    float s = rmask[b*8+h] / l;
    u16* op = ctx + ((size_t)b*Ss + row)*Dd + h*64;
    #pragma unroll
    for (int d=0; d<64; d+=2) {
      u32 w = (u32)f2b(o[d]*s) | ((u32)f2b(o[d+1]*s) << 16);
      *(u32*)(op+d) = w;
    }
  }
}

__global__ __launch_bounds__(64) void attn_row0_kernel(
    const u16* __restrict__ vl, const float* __restrict__ rmask, u16* __restrict__ ctx)
{
  int b = blockIdx.x >> 3, h = blockIdx.x & 7;
  int d = threadIdx.x;
  float s = 0.f;
  for (int j=0;j<Ss;j++) s += b2f(vl[((size_t)b*Ss+j)*Dd + h*64 + d]);
  ctx[(size_t)b*Ss*Dd + h*64 + d] = f2b(s * rmask[b*8+h] * (1.f/512.f));
}

// ---- final dot + sigmoid ----
__global__ __launch_bounds__(256) void head_kernel(
    const float* __restrict__ m2, const float* __restrict__ ow3, const float* __restrict__ ob3,
    float* __restrict__ out)
{
  int wave = threadIdx.x >> 6, lane = threadIdx.x & 63;
  int t = blockIdx.x*4 + wave;
  const float* r = m2 + (size_t)t*256;
  float s = 0.f;
  #pragma unroll
  for (int c=0;c<4;c++) s += r[lane + c*64] * ow3[lane + c*64];
  #pragma unroll
  for (int o=32;o;o>>=1) s += __shfl_down(s,o);
  if (lane==0) out[t] = 1.f/(1.f + __expf(-(s + ob3[0])));
}

// ---- host orchestration ----
static inline void gemmb(const u16* A, const u16* Wt, const float* bias, const float* Acc,
                         float* Cf, u16* Cb, int M, int N, int K, int ldw, int act,
                         hipStream_t s) {
  gemm_bf16_kernel<<<dim3(N/128, M/128), 256, 0, s>>>(A, Wt, bias, Acc, Cf, Cb, M, N, K, ldw, act);
}

extern "C" void kernel_launch(void* const* d_in, const int* in_sizes, int n_in,
                              void* d_out, int out_size, void* d_ws, size_t ws_size,
                              hipStream_t stream) {
  const int*   q_data  = (const int*)d_in[0];
  const int*   target  = (const int*)d_in[1];
  const int*   pid_data= (const int*)d_in[2];
  const float* q_tab   = (const float*)d_in[3];
  const float* qa_tab  = (const float*)d_in[4];
  const float* qd_tab  = (const float*)d_in[5];
  const float* qad_tab = (const float*)d_in[6];
  const float* pid_tab = (const float*)d_in[7];
  const float* Wq = (const float*)d_in[8];
  const float* bq = (const float*)d_in[9];
  const float* Wv = (const float*)d_in[10];
  const float* bv = (const float*)d_in[11];
  const float* Wg = (const float*)d_in[12];
  const float* Wo = (const float*)d_in[13];
  const float* bo = (const float*)d_in[14];
  const float* ln1_g = (const float*)d_in[15];
  const float* ln1_b = (const float*)d_in[16];
  const float* W1 = (const float*)d_in[17];
  const float* b1 = (const float*)d_in[18];
  const float* W2 = (const float*)d_in[19];
  const float* b2 = (const float*)d_in[20];
  const float* ln2_g = (const float*)d_in[21];
  const float* ln2_b = (const float*)d_in[22];
  const float* ow1 = (const float*)d_in[23];
  const float* ob1 = (const float*)d_in[24];
  const float* ow2 = (const float*)d_in[25];
  const float* ob2 = (const float*)d_in[26];
  const float* ow3 = (const float*)d_in[27];
  const float* ob3 = (const float*)d_in[28];

  const size_t F = (size_t)Bb*Ss*Dd;   // 6,291,456
  float* ws = (float*)d_ws;
  float* Ax = ws;            // x fp32 (LN scratch for l<2; regenerated at l=2)
  float* By = ws + F;        // y fp32 (LN scratch for l>=2)
  float* Dt = ws + 2*F;      // multiuse: ff bf16 chunk / head fp32 accum
  u16* us = (u16*)(ws + 3*F);
  u16* Fx = us;              // x bf16 shadow
  u16* Gy = us + F;          // y bf16 shadow
  u16* Hc = us + 2*F;        // ctx bf16 / x1 bf16
  u16* Iq = us + 3*F;        // q_emb bf16 (persists to head)
  u16* Jq = us + 4*F;        // ql bf16 / head h1
  u16* Kv = us + 5*F;        // vl bf16 / head m2 fp32
  u16* Ma = us + 6*F;        // attn-out bf16 / FFN-out bf16
  u16* wb = us + 7*F;        // transposed bf16 weights
  const size_t sQ = (size_t)6*512*512;
  const size_t s1 = (size_t)6*2048*512;
  u16* WqT = wb;
  u16* WvT = WqT + sQ;
  u16* WoT = WvT + sQ;
  u16* W1T = WoT + sQ;
  u16* W2T = W1T + s1;
  u16* o1T = W2T + s1;
  u16* o2T = o1T + (size_t)512*1024;
  float* rmaskb = (float*)(o2T + (size_t)256*512);

  const int M = Bb*Ss;  // 12288

  trans_kernel<<<dim3(16,16,6), 256, 0, stream>>>(Wq, WqT, 512, 512);
  trans_kernel<<<dim3(16,16,6), 256, 0, stream>>>(Wv, WvT, 512, 512);
  trans_kernel<<<dim3(16,16,6), 256, 0, stream>>>(Wo, WoT, 512, 512);
  trans_kernel<<<dim3(64,16,6), 256, 0, stream>>>(W1, W1T, 512, 2048);
  trans_kernel<<<dim3(16,64,6), 256, 0, stream>>>(W2, W2T, 2048, 512);
  trans_kernel<<<dim3(16,32,1), 256, 0, stream>>>(ow1, o1T, 1024, 512);
  trans_kernel<<<dim3(8,16,1),  256, 0, stream>>>(ow2, o2T, 512, 256);

  embed_kernel<<<M, 256, 0, stream>>>(q_data, target, pid_data, q_tab, qa_tab,
                                      qd_tab, qad_tab, pid_tab, Ax, By, Iq, Gy);

  for (int l=0; l<6; l++) {
    int strict = (l==3||l==5) ? 1 : 0;
    const u16* Qbf  = (l<2) ? Gy : (l==2 ? Iq : Fx);
    const u16* Xvbf = (l<2) ? Gy : ((l==3||l==5) ? Gy : (l==4 ? Fx : Iq));
    float* Qf   = (l<2) ? By : Ax;
    float* x1f  = (l<2) ? Ax : By;
    u16*   Qout = (l<2) ? Gy : Fx;

    if (l==2)
      embed_x_kernel<<<M, 256, 0, stream>>>(q_data, pid_data, q_tab, qd_tab, pid_tab, Ax);

    gemmb(Qbf,  WqT + (size_t)l*512*512, bq + l*512, nullptr, nullptr, Jq, M, 512, 512, 512, 0, stream);
    gemmb(Xvbf, WvT + (size_t)l*512*512, bv + l*512, nullptr, nullptr, Kv, M, 512, 512, 512, 0, stream);
    router_kernel<<<Bb, 512, 0, stream>>>(Jq, Wg + (size_t)l*512*7, rmaskb);
    attn_kernel<<<Bb*8*2, 256, 0, stream>>>(Jq, Kv, rmaskb, Hc, strict);
    attn_row0_kernel<<<Bb*8, 64, 0, stream>>>(Kv, rmaskb, Hc);
    gemmb(Hc, WoT + (size_t)l*512*512, bo + l*512, nullptr, nullptr, Ma, M, 512, 512, 512, 0, stream);
    add_ln_kernel<<<M, 256, 0, stream>>>(Qf, Ma, ln1_g + l*512, ln1_b + l*512, x1f, Hc);
    for (int c=0; c<2; c++) {
      gemmb(Hc + (size_t)c*6144*512, W1T + (size_t)l*2048*512, b1 + l*2048,
            nullptr, nullptr, (u16*)Dt, 6144, 2048, 512, 512, 1, stream);
      gemmb((u16*)Dt, W2T + (size_t)l*512*2048, b2 + l*512,
            nullptr, nullptr, Ma + (size_t)c*6144*512, 6144, 512, 2048, 2048, 0, stream);
    }
    add_ln_kernel<<<M, 256, 0, stream>>>(x1f, Ma, ln2_g + l*512, ln2_b + l*512, Qf, Qout);
  }

  gemmb(Fx, o1T,       nullptr, nullptr, Dt,         nullptr, M, 512, 512, 1024, 0, stream);
  gemmb(Iq, o1T + 512, ob1,     Dt,      nullptr,    Jq,      M, 512, 512, 1024, 1, stream);
  gemmb(Jq, o2T,       ob2,     nullptr, (float*)Kv, nullptr, M, 256, 512, 512,  1, stream);
  head_kernel<<<M/4, 256, 0, stream>>>((float*)Kv, ow3, ob3, (float*)d_out);
}

// Round 3
// 2761.175 us; speedup vs baseline: 4.3803x; 1.8520x over previous
//
#include <hip/hip_runtime.h>
#include <math.h>

typedef unsigned short u16;
typedef unsigned int   u32;
typedef __attribute__((ext_vector_type(8))) short short8;
typedef __attribute__((ext_vector_type(4))) float f32x4;

#define Bb 24
#define Ss 512
#define Dd 512
#define DFFf 2048

// ---- bf16 helpers (RNE, matches numpy) ----
__device__ __forceinline__ u16 f2b(float f) {
  u32 u = __float_as_uint(f);
  u32 r = (u + 0x7fffu + ((u >> 16) & 1u)) >> 16;
  return (u16)r;
}
__device__ __forceinline__ float b2f(u32 h) { return __uint_as_float(h << 16); }
__device__ __forceinline__ void cvt8(uint4 p, float* d) {
  d[0]=b2f(p.x&0xffffu); d[1]=b2f(p.x>>16);
  d[2]=b2f(p.y&0xffffu); d[3]=b2f(p.y>>16);
  d[4]=b2f(p.z&0xffffu); d[5]=b2f(p.z>>16);
  d[6]=b2f(p.w&0xffffu); d[7]=b2f(p.w>>16);
}

// ---- weight transpose+convert: dst[N][K] bf16 = src[K][N] fp32 ----
__global__ __launch_bounds__(256) void trans_kernel(
    const float* __restrict__ src, u16* __restrict__ dst, int K, int N)
{
  __shared__ float t[32][33];
  int n0 = blockIdx.x*32, k0 = blockIdx.y*32;
  const float* s = src + (size_t)blockIdx.z*K*N;
  u16* d = dst + (size_t)blockIdx.z*K*N;
  int c = threadIdx.x & 31, r = threadIdx.x >> 5;
  #pragma unroll
  for (int rr=r; rr<32; rr+=8) t[rr][c] = s[(size_t)(k0+rr)*N + n0 + c];
  __syncthreads();
  #pragma unroll
  for (int rr=r; rr<32; rr+=8) d[(size_t)(n0+rr)*K + k0 + c] = f2b(t[c][rr]);
}

// ---- embeddings ----
__global__ __launch_bounds__(256) void embed_kernel(
    const int* __restrict__ q_data, const int* __restrict__ target, const int* __restrict__ pid_data,
    const float* __restrict__ q_tab, const float* __restrict__ qa_tab,
    const float* __restrict__ qd_tab, const float* __restrict__ qad_tab,
    const float* __restrict__ pid_tab,
    float* __restrict__ xb, float* __restrict__ yb,
    u16* __restrict__ qebf, u16* __restrict__ ybf)
{
  int t = blockIdx.x;
  int qi = q_data[t], tg = target[t], pi = pid_data[t];
  float pd = pid_tab[pi];
  const float* qe  = q_tab  + (size_t)qi*Dd;
  const float* qa  = qa_tab + (size_t)tg*Dd;
  const float* qd  = qd_tab + (size_t)qi*Dd;
  const float* qad = qad_tab+ (size_t)tg*Dd;
  size_t base = (size_t)t*Dd;
  for (int d = threadIdx.x; d < Dd; d += 256) {
    float e = qe[d], dv = qd[d];
    float qv  = e + pd*dv;
    float qav = qa[d] + e + pd*(qad[d] + dv);
    xb[base+d] = qv;  qebf[base+d] = f2b(qv);
    yb[base+d] = qav; ybf[base+d]  = f2b(qav);
  }
}

__global__ __launch_bounds__(256) void embed_x_kernel(
    const int* __restrict__ q_data, const int* __restrict__ pid_data,
    const float* __restrict__ q_tab, const float* __restrict__ qd_tab,
    const float* __restrict__ pid_tab, float* __restrict__ xb)
{
  int t = blockIdx.x;
  int qi = q_data[t], pi = pid_data[t];
  float pd = pid_tab[pi];
  const float* qe = q_tab + (size_t)qi*Dd;
  const float* qd = qd_tab + (size_t)qi*Dd;
  size_t base = (size_t)t*Dd;
  for (int d = threadIdx.x; d < Dd; d += 256)
    xb[base+d] = qe[d] + pd*qd[d];
}

// ---- bf16 MFMA GEMM (m97 structure): C = act(A[M,K]@Wt[N,K]^T + bias (+Acc)) ----
__global__ __launch_bounds__(256) void gemm_bf16_kernel(
    const u16* __restrict__ A, const u16* __restrict__ Wt,
    const float* __restrict__ bias, const float* __restrict__ Acc,
    float* __restrict__ Cf, u16* __restrict__ Cb,
    int M, int N, int K, int ldw, int act)
{
  __shared__ u16 As[128*32];
  __shared__ u16 Bs[128*32];
  int bm = blockIdx.y*128, bn = blockIdx.x*128;
  int wv = threadIdx.x >> 6, lane = threadIdx.x & 63;
  int wm = (wv & 1)*64, wn = (wv >> 1)*64;

  const char* gA[2]; const char* gB[2];
  u32 ldsOff[2];
  #pragma unroll
  for (int t=0; t<2; t++) {
    int flat = wv*128 + t*64 + lane;
    int row = flat >> 2, cb = (flat & 3)*16;
    gA[t] = (const char*)A  + ((size_t)(bm+row)*K  )*2 + cb;
    gB[t] = (const char*)Wt + ((size_t)(bn+row)*ldw)*2 + cb;
    ldsOff[t] = (u32)(wv*128 + t*64)*16;
  }

  f32x4 acc[4][4];
  #pragma unroll
  for (int i=0;i<4;i++)
    #pragma unroll
    for (int j=0;j<4;j++) acc[i][j] = (f32x4){0.f,0.f,0.f,0.f};

  int mrow = lane & 15, quad = lane >> 4;

  for (int k0=0; k0<K; k0+=32) {
    __syncthreads();
    #pragma unroll
    for (int t=0; t<2; t++) {
      __builtin_amdgcn_global_load_lds(
          (const __attribute__((address_space(1))) void*)gA[t],
          (__attribute__((address_space(3))) void*)((char*)As + ldsOff[t]), 16, 0, 0);
      __builtin_amdgcn_global_load_lds(
          (const __attribute__((address_space(1))) void*)gB[t],
          (__attribute__((address_space(3))) void*)((char*)Bs + ldsOff[t]), 16, 0, 0);
      gA[t] += 64; gB[t] += 64;
    }
    __syncthreads();
    short8 af[4], bfr[4];
    #pragma unroll
    for (int i=0;i<4;i++) {
      af[i]  = *(const short8*)(As + (wm + i*16 + mrow)*32 + quad*8);
      bfr[i] = *(const short8*)(Bs + (wn + i*16 + mrow)*32 + quad*8);
    }
    #pragma unroll
    for (int i=0;i<4;i++)
      #pragma unroll
      for (int j=0;j<4;j++)
        acc[i][j] = __builtin_amdgcn_mfma_f32_16x16x32_bf16(af[i], bfr[j], acc[i][j], 0, 0, 0);
  }

  #pragma unroll
  for (int i=0;i<4;i++) {
    #pragma unroll
    for (int r=0;r<4;r++) {
      int row = bm + wm + i*16 + quad*4 + r;
      #pragma unroll
      for (int j=0;j<4;j++) {
        int col = bn + wn + j*16 + mrow;
        float v = acc[i][j][r];
        if (bias) v += bias[col];
        if (Acc)  v += Acc[(size_t)row*N + col];
        if (act)  v = fmaxf(v, 0.f);
        if (Cf) Cf[(size_t)row*N + col] = v;
        if (Cb) Cb[(size_t)row*N + col] = f2b(v);
      }
    }
  }
}

// ---- residual + LayerNorm ----
__device__ __forceinline__ float blockSum256(float v) {
  __shared__ float sh[4];
  #pragma unroll
  for (int o=32;o;o>>=1) v += __shfl_down(v,o);
  if ((threadIdx.x & 63)==0) sh[threadIdx.x>>6]=v;
  __syncthreads();
  float r = sh[0]+sh[1]+sh[2]+sh[3];
  __syncthreads();
  return r;
}

__global__ __launch_bounds__(256) void add_ln_kernel(
    const float* __restrict__ xa, const u16* __restrict__ xbb,
    const float* __restrict__ g, const float* __restrict__ bta,
    float* __restrict__ outf, u16* __restrict__ outb)
{
  size_t base = (size_t)blockIdx.x*Dd;
  int tid = threadIdx.x;
  float v0 = xa[base+tid]     + b2f(xbb[base+tid]);
  float v1 = xa[base+tid+256] + b2f(xbb[base+tid+256]);
  float mean = blockSum256(v0+v1) * (1.f/512.f);
  float d0 = v0-mean, d1 = v1-mean;
  float var = blockSum256(d0*d0 + d1*d1) * (1.f/512.f);
  float inv = rsqrtf(var + 1e-5f);
  float r0 = d0*inv*g[tid]     + bta[tid];
  float r1 = d1*inv*g[tid+256] + bta[tid+256];
  outf[base+tid]     = r0; outb[base+tid]     = f2b(r0);
  outf[base+tid+256] = r1; outb[base+tid+256] = f2b(r1);
}

// ---- router ----
__global__ __launch_bounds__(512) void router_kernel(
    const u16* __restrict__ ql, const float* __restrict__ Wg, float* __restrict__ rmask)
{
  __shared__ float sh[8][7];
  int b = blockIdx.x, s = threadIdx.x;
  const u16* q = ql + ((size_t)b*Ss + s)*Dd;
  float lg[7];
  #pragma unroll
  for (int k=0;k<7;k++) lg[k]=0.f;
  for (int d0=0; d0<Dd; d0+=8) {
    uint4 p = *(const uint4*)(q+d0);
    float qa[8]; cvt8(p, qa);
    #pragma unroll
    for (int i=0;i<8;i++)
      #pragma unroll
      for (int k=0;k<7;k++) lg[k] += qa[i]*Wg[(d0+i)*7+k];
  }
  float mx = lg[0];
  #pragma unroll
  for (int k=1;k<7;k++) mx = fmaxf(mx, lg[k]);
  float sum = 0.f, gt[7];
  #pragma unroll
  for (int k=0;k<7;k++){ gt[k]=__expf(lg[k]-mx); sum+=gt[k]; }
  float invs = 1.f/sum;
  #pragma unroll
  for (int k=0;k<7;k++) gt[k]*=invs;
  int i1=0; float v1=gt[0];
  #pragma unroll
  for (int k=1;k<7;k++) if (gt[k]>v1){v1=gt[k]; i1=k;}
  int i2=-1; float v2=-1e30f;
  #pragma unroll
  for (int k=0;k<7;k++) if (k!=i1 && gt[k]>v2){v2=gt[k]; i2=k;}
  #pragma unroll
  for (int k=0;k<7;k++) {
    float d = (k==i1 || k==i2) ? gt[k] : 0.f;
    #pragma unroll
    for (int o=32;o;o>>=1) d += __shfl_down(d,o);
    if ((threadIdx.x&63)==0) sh[threadIdx.x>>6][k]=d;
  }
  __syncthreads();
  if (s < 7) {
    float t=0.f;
    #pragma unroll
    for (int w=0;w<8;w++) t += sh[w][s];
    rmask[b*8 + 1 + s] = t * (1.f/512.f);
  } else if (s == 7) {
    rmask[b*8] = 1.f;
  }
}

// ---- MFMA flash attention (k==q) ----
// grid (4, B*H): blockIdx.x = 128-row Q tile, blockIdx.y = b*8+h. 4 waves.
// Wave w owns m-frags at local rows w*16 and 64+w*16 (interleaved: all waves
// share the same causal j-range). Frag layouts identical to gemm_bf16_kernel.
__global__ __launch_bounds__(256) void attn_mfma_kernel(
    const u16* __restrict__ ql, const u16* __restrict__ vl,
    const float* __restrict__ rmask, u16* __restrict__ ctx, int strict)
{
  __shared__ u16 Ks[64*64];        // K tile natural [j][k]  (B-operand layout)
  __shared__ u16 Vts[64*64];       // V tile transposed [d][j] (B-operand layout)
  __shared__ u16 Pw[4][32*72];     // per-wave P [row][j], stride 72 for bank spread
  int qt = blockIdx.x;
  int b = blockIdx.y >> 3, h = blockIdx.y & 7;
  int tid = threadIdx.x;
  int wv = tid >> 6, lane = tid & 63;
  int mrow = lane & 15, quad = lane >> 4;

  int rowbase[2];
  rowbase[0] = qt*128 + wv*16;
  rowbase[1] = rowbase[0] + 64;

  // Q A-frags: A[m=mrow][k=quad*8+j], persistent
  short8 qf[2][2];
  #pragma unroll
  for (int i=0;i<2;i++)
    #pragma unroll
    for (int kf=0;kf<2;kf++)
      qf[i][kf] = *(const short8*)(ql + (size_t)(b*Ss + rowbase[i] + mrow)*Dd + h*64 + kf*32 + quad*8);

  f32x4 O[2][4];
  #pragma unroll
  for (int i=0;i<2;i++)
    #pragma unroll
    for (int df=0;df<4;df++) O[i][df] = (f32x4){0.f,0.f,0.f,0.f};
  float mst[2][4], lst[2][4];
  #pragma unroll
  for (int i=0;i<2;i++)
    #pragma unroll
    for (int r=0;r<4;r++) { mst[i][r] = -3e38f; lst[i][r] = 0.f; }

  int nt = 2*qt + 2;
  for (int t=0; t<nt; t++) {
    int j0 = t*64;
    __syncthreads();
    // stage K tile: 512 16B chunks via global_load_lds
    #pragma unroll
    for (int s2=0; s2<2; s2++) {
      int c = s2*256 + tid;
      const char* src = (const char*)(ql + (size_t)(b*Ss + j0 + (c>>3))*Dd + h*64 + (c&7)*8);
      __builtin_amdgcn_global_load_lds(
          (const __attribute__((address_space(1))) void*)src,
          (__attribute__((address_space(3))) void*)((char*)Ks + (u32)(s2*256 + wv*64)*16), 16, 0, 0);
    }
    // stage V transposed: lane handles col j, 16 d values
    {
      int j = tid & 63, d0 = (tid >> 6) * 16;
      const u16* vp = vl + (size_t)(b*Ss + j0 + j)*Dd + h*64 + d0;
      uint4 va = *(const uint4*)vp;
      uint4 vb = *(const uint4*)(vp + 8);
      u16* col = Vts + j;
      col[(d0+0)*64]=(u16)va.x;  col[(d0+1)*64]=(u16)(va.x>>16);
      col[(d0+2)*64]=(u16)va.y;  col[(d0+3)*64]=(u16)(va.y>>16);
      col[(d0+4)*64]=(u16)va.z;  col[(d0+5)*64]=(u16)(va.z>>16);
      col[(d0+6)*64]=(u16)va.w;  col[(d0+7)*64]=(u16)(va.w>>16);
      col[(d0+8)*64]=(u16)vb.x;  col[(d0+9)*64]=(u16)(vb.x>>16);
      col[(d0+10)*64]=(u16)vb.y; col[(d0+11)*64]=(u16)(vb.y>>16);
      col[(d0+12)*64]=(u16)vb.z; col[(d0+13)*64]=(u16)(vb.z>>16);
      col[(d0+14)*64]=(u16)vb.w; col[(d0+15)*64]=(u16)(vb.w>>16);
    }
    __syncthreads();

    // S = Q @ K^T
    f32x4 s[2][4];
    #pragma unroll
    for (int n=0;n<4;n++) {
      short8 kb0 = *(const short8*)(Ks + (n*16 + mrow)*64 + quad*8);
      short8 kb1 = *(const short8*)(Ks + (n*16 + mrow)*64 + 32 + quad*8);
      #pragma unroll
      for (int i=0;i<2;i++) {
        f32x4 a = (f32x4){0.f,0.f,0.f,0.f};
        a = __builtin_amdgcn_mfma_f32_16x16x32_bf16(qf[i][0], kb0, a, 0, 0, 0);
        a = __builtin_amdgcn_mfma_f32_16x16x32_bf16(qf[i][1], kb1, a, 0, 0, 0);
        s[i][n] = a;
      }
    }
    // scale + causal mask (C layout: row=quad*4+r, col=mrow)
    #pragma unroll
    for (int i=0;i<2;i++) {
      int rb = rowbase[i] + quad*4 - strict;
      #pragma unroll
      for (int n=0;n<4;n++) {
        int j = j0 + n*16 + mrow;
        #pragma unroll
        for (int r=0;r<4;r++) {
          float v = s[i][n][r]*0.125f;
          s[i][n][r] = (j <= rb + r) ? v : -1e30f;
        }
      }
    }
    // row max across 4 n-frags + 16 lanes of the quad
    float sm[2][4], al[2][4];
    #pragma unroll
    for (int i=0;i<2;i++)
      #pragma unroll
      for (int r=0;r<4;r++) {
        float v = fmaxf(fmaxf(s[i][0][r], s[i][1][r]), fmaxf(s[i][2][r], s[i][3][r]));
        sm[i][r] = v;
      }
    #pragma unroll
    for (int off=1; off<16; off<<=1)
      #pragma unroll
      for (int i=0;i<2;i++)
        #pragma unroll
        for (int r=0;r<4;r++) sm[i][r] = fmaxf(sm[i][r], __shfl_xor(sm[i][r], off));
    #pragma unroll
    for (int i=0;i<2;i++)
      #pragma unroll
      for (int r=0;r<4;r++) {
        float mn = fmaxf(mst[i][r], sm[i][r]);
        al[i][r] = __expf(mst[i][r] - mn);
        mst[i][r] = mn;
      }
    // P = exp(s-m); write per-wave LDS; accumulate row sums
    float ps[2][4];
    #pragma unroll
    for (int i=0;i<2;i++)
      #pragma unroll
      for (int r=0;r<4;r++) ps[i][r] = 0.f;
    #pragma unroll
    for (int i=0;i<2;i++)
      #pragma unroll
      for (int n=0;n<4;n++)
        #pragma unroll
        for (int r=0;r<4;r++) {
          float p = __expf(s[i][n][r] - mst[i][r]);
          ps[i][r] += p;
          Pw[wv][(i*16 + quad*4 + r)*72 + n*16 + mrow] = f2b(p);
        }
    #pragma unroll
    for (int off=1; off<16; off<<=1)
      #pragma unroll
      for (int i=0;i<2;i++)
        #pragma unroll
        for (int r=0;r<4;r++) ps[i][r] += __shfl_xor(ps[i][r], off);
    #pragma unroll
    for (int i=0;i<2;i++)
      #pragma unroll
      for (int r=0;r<4;r++) lst[i][r] = lst[i][r]*al[i][r] + ps[i][r];
    #pragma unroll
    for (int i=0;i<2;i++)
      #pragma unroll
      for (int df=0;df<4;df++)
        #pragma unroll
        for (int r=0;r<4;r++) O[i][df][r] *= al[i][r];

    // wave-internal LDS RAW: drain writes before A-frag readback
    asm volatile("s_waitcnt lgkmcnt(0)" ::: "memory");
    short8 pf[2][2];
    #pragma unroll
    for (int pi=0; pi<2; pi++)
      #pragma unroll
      for (int kk=0; kk<2; kk++)
        pf[pi][kk] = *(const short8*)(&Pw[wv][(pi*16 + mrow)*72 + kk*32 + quad*8]);
    // O += P @ V
    #pragma unroll
    for (int df=0; df<4; df++) {
      short8 vb0 = *(const short8*)(Vts + (df*16 + mrow)*64 + quad*8);
      short8 vb1 = *(const short8*)(Vts + (df*16 + mrow)*64 + 32 + quad*8);
      #pragma unroll
      for (int i=0;i<2;i++) {
        O[i][df] = __builtin_amdgcn_mfma_f32_16x16x32_bf16(pf[i][0], vb0, O[i][df], 0, 0, 0);
        O[i][df] = __builtin_amdgcn_mfma_f32_16x16x32_bf16(pf[i][1], vb1, O[i][df], 0, 0, 0);
      }
    }
  }

  // epilogue: ctx = O * rmask / l  (row0 garbage overwritten by attn_row0_kernel)
  float rm = rmask[b*8+h];
  #pragma unroll
  for (int i=0;i<2;i++) {
    #pragma unroll
    for (int r=0;r<4;r++) {
      float sc = rm / lst[i][r];
      int grow = rowbase[i] + quad*4 + r;
      u16* op = ctx + (size_t)(b*Ss + grow)*Dd + h*64 + mrow;
      #pragma unroll
      for (int df=0;df<4;df++)
        op[df*16] = f2b(O[i][df][r]*sc);
    }
  }
}

__global__ __launch_bounds__(64) void attn_row0_kernel(
    const u16* __restrict__ vl, const float* __restrict__ rmask, u16* __restrict__ ctx)
{
  int b = blockIdx.x >> 3, h = blockIdx.x & 7;
  int d = threadIdx.x;
  float s = 0.f;
  for (int j=0;j<Ss;j++) s += b2f(vl[((size_t)b*Ss+j)*Dd + h*64 + d]);
  ctx[(size_t)b*Ss*Dd + h*64 + d] = f2b(s * rmask[b*8+h] * (1.f/512.f));
}

// ---- final dot + sigmoid ----
__global__ __launch_bounds__(256) void head_kernel(
    const float* __restrict__ m2, const float* __restrict__ ow3, const float* __restrict__ ob3,
    float* __restrict__ out)
{
  int wave = threadIdx.x >> 6, lane = threadIdx.x & 63;
  int t = blockIdx.x*4 + wave;
  const float* r = m2 + (size_t)t*256;
  float s = 0.f;
  #pragma unroll
  for (int c=0;c<4;c++) s += r[lane + c*64] * ow3[lane + c*64];
  #pragma unroll
  for (int o=32;o;o>>=1) s += __shfl_down(s,o);
  if (lane==0) out[t] = 1.f/(1.f + __expf(-(s + ob3[0])));
}

// ---- host orchestration ----
static inline void gemmb(const u16* A, const u16* Wt, const float* bias, const float* Acc,
                         float* Cf, u16* Cb, int M, int N, int K, int ldw, int act,
                         hipStream_t s) {
  gemm_bf16_kernel<<<dim3(N/128, M/128), 256, 0, s>>>(A, Wt, bias, Acc, Cf, Cb, M, N, K, ldw, act);
}

extern "C" void kernel_launch(void* const* d_in, const int* in_sizes, int n_in,
                              void* d_out, int out_size, void* d_ws, size_t ws_size,
                              hipStream_t stream) {
  const int*   q_data  = (const int*)d_in[0];
  const int*   target  = (const int*)d_in[1];
  const int*   pid_data= (const int*)d_in[2];
  const float* q_tab   = (const float*)d_in[3];
  const float* qa_tab  = (const float*)d_in[4];
  const float* qd_tab  = (const float*)d_in[5];
  const float* qad_tab = (const float*)d_in[6];
  const float* pid_tab = (const float*)d_in[7];
  const float* Wq = (const float*)d_in[8];
  const float* bq = (const float*)d_in[9];
  const float* Wv = (const float*)d_in[10];
  const float* bv = (const float*)d_in[11];
  const float* Wg = (const float*)d_in[12];
  const float* Wo = (const float*)d_in[13];
  const float* bo = (const float*)d_in[14];
  const float* ln1_g = (const float*)d_in[15];
  const float* ln1_b = (const float*)d_in[16];
  const float* W1 = (const float*)d_in[17];
  const float* b1 = (const float*)d_in[18];
  const float* W2 = (const float*)d_in[19];
  const float* b2 = (const float*)d_in[20];
  const float* ln2_g = (const float*)d_in[21];
  const float* ln2_b = (const float*)d_in[22];
  const float* ow1 = (const float*)d_in[23];
  const float* ob1 = (const float*)d_in[24];
  const float* ow2 = (const float*)d_in[25];
  const float* ob2 = (const float*)d_in[26];
  const float* ow3 = (const float*)d_in[27];
  const float* ob3 = (const float*)d_in[28];

  const size_t F = (size_t)Bb*Ss*Dd;
  float* ws = (float*)d_ws;
  float* Ax = ws;
  float* By = ws + F;
  float* Dt = ws + 2*F;
  u16* us = (u16*)(ws + 3*F);
  u16* Fx = us;
  u16* Gy = us + F;
  u16* Hc = us + 2*F;
  u16* Iq = us + 3*F;
  u16* Jq = us + 4*F;
  u16* Kv = us + 5*F;
  u16* Ma = us + 6*F;
  u16* wb = us + 7*F;
  const size_t sQ = (size_t)6*512*512;
  const size_t s1 = (size_t)6*2048*512;
  u16* WqT = wb;
  u16* WvT = WqT + sQ;
  u16* WoT = WvT + sQ;
  u16* W1T = WoT + sQ;
  u16* W2T = W1T + s1;
  u16* o1T = W2T + s1;
  u16* o2T = o1T + (size_t)512*1024;
  float* rmaskb = (float*)(o2T + (size_t)256*512);

  const int M = Bb*Ss;

  trans_kernel<<<dim3(16,16,6), 256, 0, stream>>>(Wq, WqT, 512, 512);
  trans_kernel<<<dim3(16,16,6), 256, 0, stream>>>(Wv, WvT, 512, 512);
  trans_kernel<<<dim3(16,16,6), 256, 0, stream>>>(Wo, WoT, 512, 512);
  trans_kernel<<<dim3(64,16,6), 256, 0, stream>>>(W1, W1T, 512, 2048);
  trans_kernel<<<dim3(16,64,6), 256, 0, stream>>>(W2, W2T, 2048, 512);
  trans_kernel<<<dim3(16,32,1), 256, 0, stream>>>(ow1, o1T, 1024, 512);
  trans_kernel<<<dim3(8,16,1),  256, 0, stream>>>(ow2, o2T, 512, 256);

  embed_kernel<<<M, 256, 0, stream>>>(q_data, target, pid_data, q_tab, qa_tab,
                                      qd_tab, qad_tab, pid_tab, Ax, By, Iq, Gy);

  for (int l=0; l<6; l++) {
    int strict = (l==3||l==5) ? 1 : 0;
    const u16* Qbf  = (l<2) ? Gy : (l==2 ? Iq : Fx);
    const u16* Xvbf = (l<2) ? Gy : ((l==3||l==5) ? Gy : (l==4 ? Fx : Iq));
    float* Qf   = (l<2) ? By : Ax;
    float* x1f  = (l<2) ? Ax : By;
    u16*   Qout = (l<2) ? Gy : Fx;

    if (l==2)
      embed_x_kernel<<<M, 256, 0, stream>>>(q_data, pid_data, q_tab, qd_tab, pid_tab, Ax);

    gemmb(Qbf,  WqT + (size_t)l*512*512, bq + l*512, nullptr, nullptr, Jq, M, 512, 512, 512, 0, stream);
    gemmb(Xvbf, WvT + (size_t)l*512*512, bv + l*512, nullptr, nullptr, Kv, M, 512, 512, 512, 0, stream);
    router_kernel<<<Bb, 512, 0, stream>>>(Jq, Wg + (size_t)l*512*7, rmaskb);
    attn_mfma_kernel<<<dim3(4, Bb*8), 256, 0, stream>>>(Jq, Kv, rmaskb, Hc, strict);
    attn_row0_kernel<<<Bb*8, 64, 0, stream>>>(Kv, rmaskb, Hc);
    gemmb(Hc, WoT + (size_t)l*512*512, bo + l*512, nullptr, nullptr, Ma, M, 512, 512, 512, 0, stream);
    add_ln_kernel<<<M, 256, 0, stream>>>(Qf, Ma, ln1_g + l*512, ln1_b + l*512, x1f, Hc);
    for (int c=0; c<2; c++) {
      gemmb(Hc + (size_t)c*6144*512, W1T + (size_t)l*2048*512, b1 + l*2048,
            nullptr, nullptr, (u16*)Dt, 6144, 2048, 512, 512, 1, stream);
      gemmb((u16*)Dt, W2T + (size_t)l*512*2048, b2 + l*512,
            nullptr, nullptr, Ma + (size_t)c*6144*512, 6144, 512, 2048, 2048, 0, stream);
    }
    add_ln_kernel<<<M, 256, 0, stream>>>(x1f, Ma, ln2_g + l*512, ln2_b + l*512, Qf, Qout);
  }

  gemmb(Fx, o1T,       nullptr, nullptr, Dt,         nullptr, M, 512, 512, 1024, 0, stream);
  gemmb(Iq, o1T + 512, ob1,     Dt,      nullptr,    Jq,      M, 512, 512, 1024, 1, stream);
  gemmb(Jq, o2T,       ob2,     nullptr, (float*)Kv, nullptr, M, 256, 512, 512,  1, stream);
  head_kernel<<<M/4, 256, 0, stream>>>((float*)Kv, ow3, ob3, (float*)d_out);
}